// Round 1
// baseline (981.307 us; speedup 1.0000x reference)
//
#include <hip/hip_runtime.h>
#include <cstdint>

// MultiHeadAttention: v[8,512,1024], mask[8,512,512](bool), w_kqs[2048,1024]+b,
// fc_w[1024,16384]+b -> out[8,512,1024], attn[16,8,512,512]  (all fp32 I/O)
// Internals in bf16 MFMA (threshold 1.875e-2 permits).

typedef __attribute__((ext_vector_type(8))) short short8;
typedef __attribute__((ext_vector_type(4))) float f32x4;

__device__ __forceinline__ unsigned short f2bf(float x) {
  unsigned int u = __float_as_uint(x);
  u += 0x7FFFu + ((u >> 16) & 1u);   // RNE
  return (unsigned short)(u >> 16);
}

__device__ __forceinline__ void gld16(void* lds, const void* g) {
  __builtin_amdgcn_global_load_lds(
      (const __attribute__((address_space(1))) void*)g,
      (__attribute__((address_space(3))) void*)lds, 16, 0, 0);
}

// ---------------------------------------------------------------------------
// 128x128-tile bt-GEMM core: C = A[M,K] * B[N,K]^T, bf16-in-short, f32 acc.
// 256 threads = 4 waves in 2x2; each wave 64x64 = 4x4 frags of 16x16x32 MFMA.
// LDS tiles [128][32] linear (global_load_lds), 16B-granule XOR swizzle
// (chunk ^ ((row>>1)&3)) applied on SOURCE and on READ (same involution).
// ---------------------------------------------------------------------------
__device__ __forceinline__ void gemm128(
    const short* __restrict__ A, int lda,
    const short* __restrict__ B, int ldb,
    int klen, short* ldsA, short* ldsB, f32x4 acc[4][4])
{
  const int tid = threadIdx.x;
  const int lane = tid & 63;
  const int wave = tid >> 6;
  const int wr = (wave >> 1) * 64, wc = (wave & 1) * 64;
  const int fr = lane & 15, kc = lane >> 4;

  const int g0 = tid, g1 = 256 + tid;
  const int r0 = g0 >> 2, c0 = ((g0 & 3) ^ ((r0 >> 1) & 3)) * 8;
  const int r1 = g1 >> 2, c1 = ((g1 & 3) ^ ((r1 >> 1) & 3)) * 8;
  short* ldsA0 = ldsA + wave * 512;
  short* ldsA1 = ldsA + 2048 + wave * 512;
  short* ldsB0 = ldsB + wave * 512;
  short* ldsB1 = ldsB + 2048 + wave * 512;
  const short* pa0 = A + r0 * lda + c0;
  const short* pa1 = A + r1 * lda + c1;
  const short* pb0 = B + r0 * ldb + c0;
  const short* pb1 = B + r1 * ldb + c1;

  for (int k0 = 0; k0 < klen; k0 += 32) {
    __syncthreads();                 // prev compute done before overwrite
    gld16(ldsA0, pa0 + k0);
    gld16(ldsA1, pa1 + k0);
    gld16(ldsB0, pb0 + k0);
    gld16(ldsB1, pb1 + k0);
    __syncthreads();                 // vmcnt(0) drain + barrier

    short8 af[4], bfr[4];
#pragma unroll
    for (int m = 0; m < 4; ++m) {
      int row = wr + m * 16 + fr;
      af[m] = *(const short8*)(ldsA + row * 32 + ((kc ^ ((row >> 1) & 3)) << 3));
    }
#pragma unroll
    for (int n = 0; n < 4; ++n) {
      int row = wc + n * 16 + fr;
      bfr[n] = *(const short8*)(ldsB + row * 32 + ((kc ^ ((row >> 1) & 3)) << 3));
    }
#pragma unroll
    for (int m = 0; m < 4; ++m)
#pragma unroll
      for (int n = 0; n < 4; ++n)
        acc[m][n] = __builtin_amdgcn_mfma_f32_16x16x32_bf16(af[m], bfr[n], acc[m][n], 0, 0, 0);
  }
}

#define ZERO_ACC(acc)                          \
  _Pragma("unroll") for (int m = 0; m < 4; ++m) \
  _Pragma("unroll") for (int n = 0; n < 4; ++n) \
    acc[m][n] = (f32x4){0.f, 0.f, 0.f, 0.f};

// --------------------------- KQ projection ---------------------------------
// kq[m,n] = v_bf[m,:]·w_bf[n,:] + bias[n]; scatter n -> (h=n>>7, r=n&127),
// r<64 -> K[h,b,t,r], else Q[h,b,t,r-64]
__global__ __launch_bounds__(256) void proj_kernel(
    const short* __restrict__ vb, const short* __restrict__ wb,
    const float* __restrict__ bias, short* __restrict__ kqk, short* __restrict__ kqq)
{
  __shared__ short ldsA[128 * 32], ldsB[128 * 32];
  f32x4 acc[4][4];
  ZERO_ACC(acc)
  const short* A = vb + blockIdx.y * 128 * 1024;
  const short* B = wb + blockIdx.x * 128 * 1024;
  gemm128(A, 1024, B, 1024, 1024, ldsA, ldsB, acc);

  const int lane = threadIdx.x & 63, wave = threadIdx.x >> 6;
  const int wr = (wave >> 1) * 64, wc = (wave & 1) * 64;
  const int rg = (lane >> 4) * 4, cl = lane & 15;
#pragma unroll
  for (int m = 0; m < 4; ++m)
#pragma unroll
    for (int n = 0; n < 4; ++n)
#pragma unroll
      for (int r = 0; r < 4; ++r) {
        int row = blockIdx.y * 128 + wr + m * 16 + rg + r;   // b*512+t
        int col = blockIdx.x * 128 + wc + n * 16 + cl;       // 0..2047
        float val = acc[m][n][r] + bias[col];
        int bb = row >> 9, t = row & 511;
        int h = col >> 7, rr = col & 127;
        int base = ((h * 8 + bb) * 512 + t) * 64;
        unsigned short bv = f2bf(val);
        if (rr < 64) kqk[base + rr] = (short)bv;
        else         kqq[base + rr - 64] = (short)bv;
      }
}

// ----------------------- scores + mask + softmax ----------------------------
// grid(8,128): block = 64 q-rows of one (h,b); each wave owns 16 full rows.
// K[512,64] staged in 2 halves (32KB), Q tile 8KB. acc[32] f32x4 = full row.
__global__ __launch_bounds__(256) void scores_softmax_kernel(
    const short* __restrict__ kqk, const short* __restrict__ kqq,
    const unsigned char* __restrict__ mask8, const int* __restrict__ flags,
    float* __restrict__ attn_f, short* __restrict__ attn_b)
{
  __shared__ short Kl[256 * 64];   // 32 KB
  __shared__ short Ql[64 * 64];    //  8 KB
  const int tid = threadIdx.x, lane = tid & 63, wave = tid >> 6;
  const int qt = blockIdx.x, hb = blockIdx.y, b = hb & 7;
  const int fr = lane & 15, kc = lane >> 4;
  const short* Qg = kqq + (hb * 512 + qt * 64) * 64;
  const short* Kg = kqk + hb * 512 * 64;

  f32x4 acc[32];
#pragma unroll
  for (int i = 0; i < 32; ++i) acc[i] = (f32x4){0.f, 0.f, 0.f, 0.f};

  // stage Q (rows of 64 elems = 8 granules; swizzle c ^ (row&7))
#pragma unroll
  for (int j = 0; j < 2; ++j) {
    int g = j * 256 + tid;
    int row = g >> 3, c = (g & 7) ^ (row & 7);
    gld16(Ql + (j * 256 + wave * 64) * 8, Qg + row * 64 + c * 8);
  }
  short8 aq[2];
  for (int half = 0; half < 2; ++half) {
#pragma unroll
    for (int j = 0; j < 8; ++j) {
      int g = j * 256 + tid;
      int row = g >> 3, c = (g & 7) ^ (row & 7);
      gld16(Kl + (j * 256 + wave * 64) * 8, Kg + (half * 256 + row) * 64 + c * 8);
    }
    __syncthreads();
    if (half == 0) {
      int qrow = wave * 16 + fr;
#pragma unroll
      for (int s = 0; s < 2; ++s)
        aq[s] = *(const short8*)(Ql + qrow * 64 + (((s * 4 + kc) ^ (qrow & 7)) << 3));
    }
#pragma unroll
    for (int n = 0; n < 16; ++n) {
      int krow = n * 16 + fr;
      short8 b0 = *(const short8*)(Kl + krow * 64 + ((kc ^ (krow & 7)) << 3));
      short8 b1 = *(const short8*)(Kl + krow * 64 + (((4 + kc) ^ (krow & 7)) << 3));
      acc[half * 16 + n] = __builtin_amdgcn_mfma_f32_16x16x32_bf16(aq[0], b0, acc[half * 16 + n], 0, 0, 0);
      acc[half * 16 + n] = __builtin_amdgcn_mfma_f32_16x16x32_bf16(aq[1], b1, acc[half * 16 + n], 0, 0, 0);
    }
    if (half == 0) __syncthreads();   // compute done before restaging Kl
  }

  // ---- mask + scale + softmax (rows live in-register; reduce over 16 lanes)
  const int f_byte = flags[0], f_f32 = flags[1];
  const int* mask32 = (const int*)mask8;
  const float* maskf = (const float*)mask8;
  const int qbase = qt * 64 + wave * 16 + (lane >> 4) * 4;

  float mrow[4] = {-3.0e38f, -3.0e38f, -3.0e38f, -3.0e38f};
#pragma unroll
  for (int n = 0; n < 32; ++n) {
    int col = n * 16 + fr;
#pragma unroll
    for (int r = 0; r < 4; ++r) {
      int midx = (b * 512 + qbase + r) * 512 + col;
      bool msk = f_byte ? (mask8[midx] != 0)
                        : (f_f32 ? (maskf[midx] != 0.0f) : (mask32[midx] != 0));
      float s = msk ? -100000.0f : acc[n][r] * 0.125f;
      acc[n][r] = s;
      mrow[r] = fmaxf(mrow[r], s);
    }
  }
#pragma unroll
  for (int r = 0; r < 4; ++r) {
    float v = mrow[r];
    v = fmaxf(v, __shfl_xor(v, 1));
    v = fmaxf(v, __shfl_xor(v, 2));
    v = fmaxf(v, __shfl_xor(v, 4));
    v = fmaxf(v, __shfl_xor(v, 8));
    mrow[r] = v;
  }
  float srow[4] = {0.f, 0.f, 0.f, 0.f};
#pragma unroll
  for (int n = 0; n < 32; ++n)
#pragma unroll
    for (int r = 0; r < 4; ++r) {
      float p = __expf(acc[n][r] - mrow[r]);
      acc[n][r] = p;
      srow[r] += p;
    }
#pragma unroll
  for (int r = 0; r < 4; ++r) {
    float v = srow[r];
    v += __shfl_xor(v, 1);
    v += __shfl_xor(v, 2);
    v += __shfl_xor(v, 4);
    v += __shfl_xor(v, 8);
    srow[r] = 1.0f / v;
  }
  const long obase = (long)hb * 512 * 512;
#pragma unroll
  for (int n = 0; n < 32; ++n) {
    int col = n * 16 + fr;
#pragma unroll
    for (int r = 0; r < 4; ++r) {
      long idx = obase + (long)(qbase + r) * 512 + col;
      float p = acc[n][r] * srow[r];
      attn_f[idx] = p;
      attn_b[idx] = (short)f2bf(p);
    }
  }
}

// ------------------------------- PV ----------------------------------------
__global__ __launch_bounds__(256) void pv_kernel(
    const short* __restrict__ attn_b, const short* __restrict__ vT,
    short* __restrict__ out_pre)
{
  __shared__ short ldsA[128 * 32], ldsB[128 * 32];
  f32x4 acc[4][4];
  ZERO_ACC(acc)
  const int z = blockIdx.y, h = z >> 3, b = z & 7;
  const int tm = blockIdx.x >> 3, tn = blockIdx.x & 7;
  const short* A = attn_b + (z * 512 + tm * 128) * 512;
  const short* B = vT + (b * 1024 + tn * 128) * 512;
  gemm128(A, 512, B, 512, 512, ldsA, ldsB, acc);

  const int lane = threadIdx.x & 63, wave = threadIdx.x >> 6;
  const int wr = (wave >> 1) * 64, wc = (wave & 1) * 64;
  const int rg = (lane >> 4) * 4, cl = lane & 15;
#pragma unroll
  for (int m = 0; m < 4; ++m)
#pragma unroll
    for (int n = 0; n < 4; ++n)
#pragma unroll
      for (int r = 0; r < 4; ++r) {
        int q = tm * 128 + wr + m * 16 + rg + r;
        int c = tn * 128 + wc + n * 16 + cl;
        out_pre[((b * 512 + q) * 16 + h) * 1024 + c] = (short)f2bf(acc[m][n][r]);
      }
}

// ------------------------------- FC (split-K=4) -----------------------------
__global__ __launch_bounds__(256) void fc_kernel(
    const short* __restrict__ outp, const short* __restrict__ fcw,
    float* __restrict__ part)
{
  __shared__ short ldsA[128 * 32], ldsB[128 * 32];
  f32x4 acc[4][4];
  ZERO_ACC(acc)
  const int kz = blockIdx.z;
  const short* A = outp + blockIdx.y * 128 * 16384 + kz * 4096;
  const short* B = fcw + blockIdx.x * 128 * 16384 + kz * 4096;
  gemm128(A, 16384, B, 16384, 4096, ldsA, ldsB, acc);

  float* P = part + kz * 4096 * 1024;
  const int lane = threadIdx.x & 63, wave = threadIdx.x >> 6;
  const int wr = (wave >> 1) * 64, wc = (wave & 1) * 64;
  const int rg = (lane >> 4) * 4, cl = lane & 15;
#pragma unroll
  for (int m = 0; m < 4; ++m)
#pragma unroll
    for (int n = 0; n < 4; ++n)
#pragma unroll
      for (int r = 0; r < 4; ++r) {
        int row = blockIdx.y * 128 + wr + m * 16 + rg + r;
        int col = blockIdx.x * 128 + wc + n * 16 + cl;
        P[row * 1024 + col] = acc[m][n][r];
      }
}

__global__ void fc_reduce_kernel(const float* __restrict__ part,
                                 const float* __restrict__ fcb,
                                 float* __restrict__ out)
{
  int i = blockIdx.x * 256 + threadIdx.x;    // over 1048576 float4 groups
  f32x4 s = ((const f32x4*)part)[i];
  s += ((const f32x4*)(part + 4194304))[i];
  s += ((const f32x4*)(part + 2 * 4194304))[i];
  s += ((const f32x4*)(part + 3 * 4194304))[i];
  int j = (i * 4) & 1023;
  f32x4 bias = *(const f32x4*)(fcb + j);
  ((f32x4*)out)[i] = s + bias;
}

// ------------------------------- utilities ----------------------------------
__global__ void cvt_kernel(const float* __restrict__ in, short* __restrict__ out, int n8) {
  int i = blockIdx.x * 256 + threadIdx.x;
  if (i >= n8) return;
  f32x4 x0 = ((const f32x4*)in)[i * 2];
  f32x4 x1 = ((const f32x4*)in)[i * 2 + 1];
  short8 o;
  o[0] = (short)f2bf(x0[0]); o[1] = (short)f2bf(x0[1]);
  o[2] = (short)f2bf(x0[2]); o[3] = (short)f2bf(x0[3]);
  o[4] = (short)f2bf(x1[0]); o[5] = (short)f2bf(x1[1]);
  o[6] = (short)f2bf(x1[2]); o[7] = (short)f2bf(x1[3]);
  ((short8*)out)[i] = o;
}

// v[8,512,1024] f32 -> vT[8,1024,512] bf16
__global__ void transpose_kernel(const float* __restrict__ v, short* __restrict__ vT) {
  __shared__ float tile[32][33];
  int b = blockIdx.z, t0 = blockIdx.y * 32, c0 = blockIdx.x * 32;
  int tx = threadIdx.x, ty = threadIdx.y;   // 32 x 8
  const float* src = v + (b * 512 + t0) * 1024 + c0;
#pragma unroll
  for (int i = 0; i < 4; ++i)
    tile[ty + i * 8][tx] = src[(ty + i * 8) * 1024 + tx];
  __syncthreads();
  short* dst = vT + (b * 1024 + c0) * 512 + t0;
#pragma unroll
  for (int i = 0; i < 4; ++i)
    dst[(ty + i * 8) * 512 + tx] = (short)f2bf(tile[tx][ty + i * 8]);
}

// mask layout detector: bytes at idx%4==1 nonzero -> int8/bool layout;
// else bytes at %4 in {2,3} nonzero -> f32 layout; else int32 layout.
__global__ void detect_kernel(const unsigned int* __restrict__ m, int nwords, int* flags) {
  int i = blockIdx.x * 256 + threadIdx.x;
  unsigned int f0 = 0, f1 = 0;
  for (int idx = i; idx < nwords; idx += gridDim.x * 256) {
    unsigned int u = m[idx];
    f0 |= (u >> 8) & 0xFFu;
    f1 |= u & 0xFFFF0000u;
  }
  int b0 = __any(f0 != 0), b1 = __any(f1 != 0);
  if ((threadIdx.x & 63) == 0) {
    if (b0) atomicOr(flags, 1);
    if (b1) atomicOr(flags + 1, 1);
  }
}

// ---------------------------------------------------------------------------
extern "C" void kernel_launch(void* const* d_in, const int* in_sizes, int n_in,
                              void* d_out, int out_size, void* d_ws, size_t ws_size,
                              hipStream_t stream) {
  const float* v   = (const float*)d_in[0];
  const unsigned char* mask = (const unsigned char*)d_in[1];
  const float* wkq = (const float*)d_in[2];
  const float* bkq = (const float*)d_in[3];
  const float* fcw = (const float*)d_in[4];
  const float* fcb = (const float*)d_in[5];
  float* out    = (float*)d_out;
  float* attn_f = out + 4194304;           // out[4,194,304] then attn[33,554,432]

  char* ws = (char*)d_ws;
  int*   flags = (int*)ws;
  short* vb    = (short*)(ws + 256);                  //  8 MB  v bf16 [4096,1024]
  short* vt    = (short*)(ws + 8388864);              //  8 MB  vT bf16 [8,1024,512]
  short* wkqb  = (short*)(ws + 16777472);             //  4 MB  w_kqs bf16
  short* fcwb  = (short*)(ws + 20971776);             // 32 MB  fc_w bf16
  short* kqk   = (short*)(ws + 54526208);             //  8 MB  K [16,8,512,64]
  short* kqq   = (short*)(ws + 62914816);             //  8 MB  Q [16,8,512,64]
  short* attnb = (short*)(ws + 71303424);             // 64 MB  attn bf16
  short* outp  = (short*)(ws + 138412288);            //128 MB  out_pre [4096,16384]
  float* part  = (float*)(ws + 71303424);             // 64 MB  fc partials (aliases attnb; dead by then)

  hipMemsetAsync(d_ws, 0, 64, stream);
  detect_kernel<<<256, 256, 0, stream>>>((const unsigned int*)mask, 524288, flags);
  cvt_kernel<<<2048, 256, 0, stream>>>(v, vb, 524288);
  transpose_kernel<<<dim3(32, 16, 8), dim3(32, 8), 0, stream>>>(v, vt);
  cvt_kernel<<<1024, 256, 0, stream>>>(wkq, wkqb, 262144);
  cvt_kernel<<<8192, 256, 0, stream>>>(fcw, fcwb, 2097152);
  proj_kernel<<<dim3(16, 32), 256, 0, stream>>>(vb, wkqb, bkq, kqk, kqq);
  scores_softmax_kernel<<<dim3(8, 128), 256, 0, stream>>>(kqk, kqq, mask, flags, attn_f, attnb);
  pv_kernel<<<dim3(32, 128), 256, 0, stream>>>(attnb, vt, outp);
  fc_kernel<<<dim3(8, 32, 4), 256, 0, stream>>>(outp, fcwb, part);
  fc_reduce_kernel<<<4096, 256, 0, stream>>>(part, fcb, out);
}

// Round 2
// 725.053 us; speedup vs baseline: 1.3534x; 1.3534x over previous
//
#include <hip/hip_runtime.h>
#include <cstdint>

// MultiHeadAttention: v[8,512,1024], mask[8,512,512](bool), w_kqs[2048,1024]+b,
// fc_w[1024,16384]+b -> out[8,512,1024], attn[16,8,512,512]  (all fp32 I/O)
// Internals in bf16 MFMA. R2: 2-phase double-buffered GEMM core (raw s_barrier +
// manual vmcnt, setprio), 256x128 tiles for PV/FC, XCD-swizzle for FC.

typedef __attribute__((ext_vector_type(8))) short short8;
typedef __attribute__((ext_vector_type(4))) float f32x4;

__device__ __forceinline__ unsigned short f2bf(float x) {
  unsigned int u = __float_as_uint(x);
  u += 0x7FFFu + ((u >> 16) & 1u);   // RNE
  return (unsigned short)(u >> 16);
}

__device__ __forceinline__ void gld16(void* lds, const void* g) {
  __builtin_amdgcn_global_load_lds(
      (const __attribute__((address_space(1))) void*)g,
      (__attribute__((address_space(3))) void*)lds, 16, 0, 0);
}

// ---------------------------------------------------------------------------
// bt-GEMM core, 2-phase double-buffered: C = A[M,K] * B[N,K]^T, bf16, f32 acc.
// BM in {128,256}, BN=128, BK=32, THREADS=2*BM (4 or 8 waves, 64x64 per wave).
// LDS [rows][32] linear (global_load_lds dest), 16B-granule XOR swizzle
// (chunk ^ ((row>>1)&3)) applied on SOURCE addr and on READ (same involution).
// Pipeline per iter: stage(next buf) || ds_read+MFMA(cur buf); vmcnt(0); s_barrier.
// Safety: barrier at end of iter t guarantees all waves' ds_reads of buf cur
// completed (MFMA consumed them) before iter t+1 stages into it.
// ---------------------------------------------------------------------------
template<int BM>
__device__ __forceinline__ void gemm_bt(
    const short* __restrict__ A, int lda,
    const short* __restrict__ B, int ldb,
    int klen, short* __restrict__ ldsA, short* __restrict__ ldsB,
    f32x4 acc[4][4])
{
  constexpr int THREADS = 2 * BM;
  constexpr int ABUF = BM * 32;       // shorts per A buffer
  constexpr int BBUF = 128 * 32;
  const int tid = (int)threadIdx.x, lane = tid & 63, wave = tid >> 6;
  const int wr = (wave >> 1) * 64, wc = (wave & 1) * 64;
  const int fr = lane & 15, kc = lane >> 4;

  const int ra0 = tid >> 2,             ca0 = ((tid & 3) ^ ((ra0 >> 1) & 3)) << 3;
  const int a1  = tid + THREADS;
  const int ra1 = a1 >> 2,              ca1 = ((a1 & 3) ^ ((ra1 >> 1) & 3)) << 3;
  const short* pa0 = A + ra0 * lda + ca0;
  const short* pa1 = A + ra1 * lda + ca1;
  const int bg0 = tid & 511;
  const int rb0 = bg0 >> 2,             cb0 = ((bg0 & 3) ^ ((rb0 >> 1) & 3)) << 3;
  const short* pb0 = B + rb0 * ldb + cb0;
  const short* pb1 = nullptr;
  if constexpr (THREADS == 256) {
    const int b1 = tid + 256;
    const int rb1 = b1 >> 2, cb1 = ((b1 & 3) ^ ((rb1 >> 1) & 3)) << 3;
    pb1 = B + rb1 * ldb + cb1;
  }
  const int aw = wave * 512;  // wave-uniform LDS dest (shorts); HW adds lane*16B

  auto stage = [&](int buf, int k0) {
    short* dA = ldsA + buf * ABUF;
    short* dB = ldsB + buf * BBUF;
    gld16(dA + aw, pa0 + k0);
    gld16(dA + THREADS * 8 + aw, pa1 + k0);
    gld16(dB + aw, pb0 + k0);
    if constexpr (THREADS == 256) gld16(dB + 2048 + aw, pb1 + k0);
  };

  stage(0, 0);
  asm volatile("s_waitcnt vmcnt(0)" ::: "memory");
  __builtin_amdgcn_s_barrier();

  const int nt = klen >> 5;
  int cur = 0;
  for (int t = 0; t < nt; ++t) {
    if (t + 1 < nt) stage(cur ^ 1, (t + 1) << 5);
    const short* bufA = ldsA + cur * ABUF;
    const short* bufB = ldsB + cur * BBUF;
    short8 af[4], bq[4];
#pragma unroll
    for (int m = 0; m < 4; ++m) {
      int row = wr + m * 16 + fr;
      af[m] = *(const short8*)(bufA + row * 32 + ((kc ^ ((row >> 1) & 3)) << 3));
    }
#pragma unroll
    for (int n = 0; n < 4; ++n) {
      int row = wc + n * 16 + fr;
      bq[n] = *(const short8*)(bufB + row * 32 + ((kc ^ ((row >> 1) & 3)) << 3));
    }
    __builtin_amdgcn_s_setprio(1);
#pragma unroll
    for (int m = 0; m < 4; ++m)
#pragma unroll
      for (int n = 0; n < 4; ++n)
        acc[m][n] = __builtin_amdgcn_mfma_f32_16x16x32_bf16(af[m], bq[n], acc[m][n], 0, 0, 0);
    __builtin_amdgcn_s_setprio(0);
    asm volatile("s_waitcnt vmcnt(0)" ::: "memory");
    __builtin_amdgcn_s_barrier();
    cur ^= 1;
  }
}

#define ZERO_ACC(acc)                          \
  _Pragma("unroll") for (int m = 0; m < 4; ++m) \
  _Pragma("unroll") for (int n = 0; n < 4; ++n) \
    acc[m][n] = (f32x4){0.f, 0.f, 0.f, 0.f};

// --------------------------- KQ projection ---------------------------------
__global__ __launch_bounds__(256) void proj_kernel(
    const short* __restrict__ vb, const short* __restrict__ wb,
    const float* __restrict__ bias, short* __restrict__ kqk, short* __restrict__ kqq)
{
  __shared__ short ldsA[2 * 128 * 32], ldsB[2 * 128 * 32];
  f32x4 acc[4][4];
  ZERO_ACC(acc)
  const short* A = vb + blockIdx.y * 128 * 1024;
  const short* B = wb + blockIdx.x * 128 * 1024;
  gemm_bt<128>(A, 1024, B, 1024, 1024, ldsA, ldsB, acc);

  const int lane = threadIdx.x & 63, wave = threadIdx.x >> 6;
  const int wr = (wave >> 1) * 64, wc = (wave & 1) * 64;
  const int rg = (lane >> 4) * 4, cl = lane & 15;
#pragma unroll
  for (int m = 0; m < 4; ++m)
#pragma unroll
    for (int n = 0; n < 4; ++n)
#pragma unroll
      for (int r = 0; r < 4; ++r) {
        int row = blockIdx.y * 128 + wr + m * 16 + rg + r;   // b*512+t
        int col = blockIdx.x * 128 + wc + n * 16 + cl;       // 0..2047
        float val = acc[m][n][r] + bias[col];
        int bb = row >> 9, t = row & 511;
        int h = col >> 7, rr = col & 127;
        int base = ((h * 8 + bb) * 512 + t) * 64;
        unsigned short bv = f2bf(val);
        if (rr < 64) kqk[base + rr] = (short)bv;
        else         kqq[base + rr - 64] = (short)bv;
      }
}

// ----------------------- scores + mask + softmax ----------------------------
__global__ __launch_bounds__(256) void scores_softmax_kernel(
    const short* __restrict__ kqk, const short* __restrict__ kqq,
    const unsigned char* __restrict__ mask8, const int* __restrict__ flags,
    float* __restrict__ attn_f, short* __restrict__ attn_b)
{
  __shared__ short Kl[256 * 64];   // 32 KB
  __shared__ short Ql[64 * 64];    //  8 KB
  const int tid = threadIdx.x, lane = tid & 63, wave = tid >> 6;
  const int qt = blockIdx.x, hb = blockIdx.y, b = hb & 7;
  const int fr = lane & 15, kc = lane >> 4;
  const short* Qg = kqq + (hb * 512 + qt * 64) * 64;
  const short* Kg = kqk + hb * 512 * 64;

  f32x4 acc[32];
#pragma unroll
  for (int i = 0; i < 32; ++i) acc[i] = (f32x4){0.f, 0.f, 0.f, 0.f};

#pragma unroll
  for (int j = 0; j < 2; ++j) {
    int g = j * 256 + tid;
    int row = g >> 3, c = (g & 7) ^ (row & 7);
    gld16(Ql + (j * 256 + wave * 64) * 8, Qg + row * 64 + c * 8);
  }
  short8 aq[2];
  for (int half = 0; half < 2; ++half) {
#pragma unroll
    for (int j = 0; j < 8; ++j) {
      int g = j * 256 + tid;
      int row = g >> 3, c = (g & 7) ^ (row & 7);
      gld16(Kl + (j * 256 + wave * 64) * 8, Kg + (half * 256 + row) * 64 + c * 8);
    }
    __syncthreads();
    if (half == 0) {
      int qrow = wave * 16 + fr;
#pragma unroll
      for (int s = 0; s < 2; ++s)
        aq[s] = *(const short8*)(Ql + qrow * 64 + (((s * 4 + kc) ^ (qrow & 7)) << 3));
    }
#pragma unroll
    for (int n = 0; n < 16; ++n) {
      int krow = n * 16 + fr;
      short8 b0 = *(const short8*)(Kl + krow * 64 + ((kc ^ (krow & 7)) << 3));
      short8 b1 = *(const short8*)(Kl + krow * 64 + (((4 + kc) ^ (krow & 7)) << 3));
      acc[half * 16 + n] = __builtin_amdgcn_mfma_f32_16x16x32_bf16(aq[0], b0, acc[half * 16 + n], 0, 0, 0);
      acc[half * 16 + n] = __builtin_amdgcn_mfma_f32_16x16x32_bf16(aq[1], b1, acc[half * 16 + n], 0, 0, 0);
    }
    if (half == 0) __syncthreads();
  }

  const int f_byte = flags[0], f_f32 = flags[1];
  const int* mask32 = (const int*)mask8;
  const float* maskf = (const float*)mask8;
  const int qbase = qt * 64 + wave * 16 + (lane >> 4) * 4;

  float mrow[4] = {-3.0e38f, -3.0e38f, -3.0e38f, -3.0e38f};
#pragma unroll
  for (int n = 0; n < 32; ++n) {
    int col = n * 16 + fr;
#pragma unroll
    for (int r = 0; r < 4; ++r) {
      int midx = (b * 512 + qbase + r) * 512 + col;
      bool msk = f_byte ? (mask8[midx] != 0)
                        : (f_f32 ? (maskf[midx] != 0.0f) : (mask32[midx] != 0));
      float s = msk ? -100000.0f : acc[n][r] * 0.125f;
      acc[n][r] = s;
      mrow[r] = fmaxf(mrow[r], s);
    }
  }
#pragma unroll
  for (int r = 0; r < 4; ++r) {
    float v = mrow[r];
    v = fmaxf(v, __shfl_xor(v, 1));
    v = fmaxf(v, __shfl_xor(v, 2));
    v = fmaxf(v, __shfl_xor(v, 4));
    v = fmaxf(v, __shfl_xor(v, 8));
    mrow[r] = v;
  }
  float srow[4] = {0.f, 0.f, 0.f, 0.f};
#pragma unroll
  for (int n = 0; n < 32; ++n)
#pragma unroll
    for (int r = 0; r < 4; ++r) {
      float p = __expf(acc[n][r] - mrow[r]);
      acc[n][r] = p;
      srow[r] += p;
    }
#pragma unroll
  for (int r = 0; r < 4; ++r) {
    float v = srow[r];
    v += __shfl_xor(v, 1);
    v += __shfl_xor(v, 2);
    v += __shfl_xor(v, 4);
    v += __shfl_xor(v, 8);
    srow[r] = 1.0f / v;
  }
  const long obase = (long)hb * 512 * 512;
#pragma unroll
  for (int n = 0; n < 32; ++n) {
    int col = n * 16 + fr;
#pragma unroll
    for (int r = 0; r < 4; ++r) {
      long idx = obase + (long)(qbase + r) * 512 + col;
      float p = acc[n][r] * srow[r];
      attn_f[idx] = p;
      attn_b[idx] = (short)f2bf(p);
    }
  }
}

// ------------------------------- PV (256x128) -------------------------------
__global__ __launch_bounds__(512, 4) void pv_kernel(
    const short* __restrict__ attn_b, const short* __restrict__ vT,
    short* __restrict__ out_pre)
{
  __shared__ short ldsA[2 * 256 * 32], ldsB[2 * 128 * 32];   // 32 + 16 KB
  f32x4 acc[4][4];
  ZERO_ACC(acc)
  const int L = blockIdx.x;
  const int x = L & 7, y = (L >> 3) & 1, z = L >> 4;   // z = h*8+b
  const int h = z >> 3, b = z & 7;
  const short* A = attn_b + (z * 512 + y * 256) * 512;
  const short* B = vT + (b * 1024 + x * 128) * 512;
  gemm_bt<256>(A, 512, B, 512, 512, ldsA, ldsB, acc);

  const int lane = threadIdx.x & 63, wave = threadIdx.x >> 6;
  const int wr = (wave >> 1) * 64, wc = (wave & 1) * 64;
  const int rg = (lane >> 4) * 4, cl = lane & 15;
#pragma unroll
  for (int m = 0; m < 4; ++m)
#pragma unroll
    for (int n = 0; n < 4; ++n)
#pragma unroll
      for (int r = 0; r < 4; ++r) {
        int q = y * 256 + wr + m * 16 + rg + r;
        int c = x * 128 + wc + n * 16 + cl;
        out_pre[((b * 512 + q) * 16 + h) * 1024 + c] = (short)f2bf(acc[m][n][r]);
      }
}

// --------------------------- FC (256x128, split-K=4) ------------------------
// XCD swizzle: co-locate the 8 N-blocks sharing an A-band (and their B-tiles)
// on one XCD so A-refetch L2-hits. 512 blocks, nwg%8==0 -> bijective.
__global__ __launch_bounds__(512, 4) void fc_kernel(
    const short* __restrict__ outp, const short* __restrict__ fcw,
    float* __restrict__ part)
{
  __shared__ short ldsA[2 * 256 * 32], ldsB[2 * 128 * 32];
  f32x4 acc[4][4];
  ZERO_ACC(acc)
  const int L = blockIdx.x;
  const int xcd = L & 7, s = L >> 3;
  const int x = s & 7;                      // N-tile (128 cols)
  const int band = xcd * 8 + (s >> 3);      // 64 (y,z) bands
  const int y = band & 15, kz = band >> 4;  // y: M-tile (256 rows), kz: split-K
  const short* A = outp + y * 256 * 16384 + kz * 4096;
  const short* B = fcw + x * 128 * 16384 + kz * 4096;
  gemm_bt<256>(A, 16384, B, 16384, 4096, ldsA, ldsB, acc);

  float* P = part + kz * 4194304;
  const int lane = threadIdx.x & 63, wave = threadIdx.x >> 6;
  const int wr = (wave >> 1) * 64, wc = (wave & 1) * 64;
  const int rg = (lane >> 4) * 4, cl = lane & 15;
#pragma unroll
  for (int m = 0; m < 4; ++m)
#pragma unroll
    for (int n = 0; n < 4; ++n)
#pragma unroll
      for (int r = 0; r < 4; ++r) {
        int row = y * 256 + wr + m * 16 + rg + r;
        int col = x * 128 + wc + n * 16 + cl;
        P[row * 1024 + col] = acc[m][n][r];
      }
}

__global__ void fc_reduce_kernel(const float* __restrict__ part,
                                 const float* __restrict__ fcb,
                                 float* __restrict__ out)
{
  int i = blockIdx.x * 256 + threadIdx.x;    // over 1048576 float4 groups
  f32x4 s = ((const f32x4*)part)[i];
  s += ((const f32x4*)(part + 4194304))[i];
  s += ((const f32x4*)(part + 2 * 4194304))[i];
  s += ((const f32x4*)(part + 3 * 4194304))[i];
  int j = (i * 4) & 1023;
  f32x4 bias = *(const f32x4*)(fcb + j);
  ((f32x4*)out)[i] = s + bias;
}

// ------------------------------- utilities ----------------------------------
__global__ void cvt_kernel(const float* __restrict__ in, short* __restrict__ out, int n8) {
  int i = blockIdx.x * 256 + threadIdx.x;
  if (i >= n8) return;
  f32x4 x0 = ((const f32x4*)in)[i * 2];
  f32x4 x1 = ((const f32x4*)in)[i * 2 + 1];
  short8 o;
  o[0] = (short)f2bf(x0[0]); o[1] = (short)f2bf(x0[1]);
  o[2] = (short)f2bf(x0[2]); o[3] = (short)f2bf(x0[3]);
  o[4] = (short)f2bf(x1[0]); o[5] = (short)f2bf(x1[1]);
  o[6] = (short)f2bf(x1[2]); o[7] = (short)f2bf(x1[3]);
  ((short8*)out)[i] = o;
}

// v[8,512,1024] f32 -> vT[8,1024,512] bf16
__global__ void transpose_kernel(const float* __restrict__ v, short* __restrict__ vT) {
  __shared__ float tile[32][33];
  int b = blockIdx.z, t0 = blockIdx.y * 32, c0 = blockIdx.x * 32;
  int tx = threadIdx.x, ty = threadIdx.y;   // 32 x 8
  const float* src = v + (b * 512 + t0) * 1024 + c0;
#pragma unroll
  for (int i = 0; i < 4; ++i)
    tile[ty + i * 8][tx] = src[(ty + i * 8) * 1024 + tx];
  __syncthreads();
  short* dst = vT + (b * 1024 + c0) * 512 + t0;
#pragma unroll
  for (int i = 0; i < 4; ++i)
    dst[(ty + i * 8) * 512 + tx] = (short)f2bf(tile[tx][ty + i * 8]);
}

__global__ void detect_kernel(const unsigned int* __restrict__ m, int nwords, int* flags) {
  int i = blockIdx.x * 256 + threadIdx.x;
  unsigned int f0 = 0, f1 = 0;
  for (int idx = i; idx < nwords; idx += gridDim.x * 256) {
    unsigned int u = m[idx];
    f0 |= (u >> 8) & 0xFFu;
    f1 |= u & 0xFFFF0000u;
  }
  int b0 = __any(f0 != 0), b1 = __any(f1 != 0);
  if ((threadIdx.x & 63) == 0) {
    if (b0) atomicOr(flags, 1);
    if (b1) atomicOr(flags + 1, 1);
  }
}

// ---------------------------------------------------------------------------
extern "C" void kernel_launch(void* const* d_in, const int* in_sizes, int n_in,
                              void* d_out, int out_size, void* d_ws, size_t ws_size,
                              hipStream_t stream) {
  const float* v   = (const float*)d_in[0];
  const unsigned char* mask = (const unsigned char*)d_in[1];
  const float* wkq = (const float*)d_in[2];
  const float* bkq = (const float*)d_in[3];
  const float* fcw = (const float*)d_in[4];
  const float* fcb = (const float*)d_in[5];
  float* out    = (float*)d_out;
  float* attn_f = out + 4194304;

  char* ws = (char*)d_ws;
  int*   flags = (int*)ws;
  short* vb    = (short*)(ws + 256);                  //  8 MB
  short* vt    = (short*)(ws + 8388864);              //  8 MB
  short* wkqb  = (short*)(ws + 16777472);             //  4 MB
  short* fcwb  = (short*)(ws + 20971776);             // 32 MB
  short* kqk   = (short*)(ws + 54526208);             //  8 MB
  short* kqq   = (short*)(ws + 62914816);             //  8 MB
  short* attnb = (short*)(ws + 71303424);             // 64 MB
  short* outp  = (short*)(ws + 138412288);            //128 MB
  float* part  = (float*)(ws + 71303424);             // 64 MB (aliases attnb; dead by then)

  hipMemsetAsync(d_ws, 0, 64, stream);
  detect_kernel<<<256, 256, 0, stream>>>((const unsigned int*)mask, 524288, flags);
  cvt_kernel<<<2048, 256, 0, stream>>>(v, vb, 524288);
  transpose_kernel<<<dim3(32, 16, 8), dim3(32, 8), 0, stream>>>(v, vt);
  cvt_kernel<<<1024, 256, 0, stream>>>(wkq, wkqb, 262144);
  cvt_kernel<<<8192, 256, 0, stream>>>(fcw, fcwb, 2097152);
  proj_kernel<<<dim3(16, 32), 256, 0, stream>>>(vb, wkqb, bkq, kqk, kqq);
  scores_softmax_kernel<<<dim3(8, 128), 256, 0, stream>>>(kqk, kqq, mask, flags, attn_f, attnb);
  pv_kernel<<<2048, 512, 0, stream>>>(attnb, vt, outp);
  fc_kernel<<<512, 512, 0, stream>>>(outp, fcwb, part);
  fc_reduce_kernel<<<4096, 256, 0, stream>>>(part, fcb, out);
}